// Round 11
// baseline (446.859 us; speedup 1.0000x reference)
//
#include <hip/hip_runtime.h>
#include <stdint.h>

typedef __attribute__((ext_vector_type(8))) short s16x8;
typedef __attribute__((ext_vector_type(4))) float f32x4;

__device__ __forceinline__ short f2bf(float x) {
  uint32_t u = __builtin_bit_cast(uint32_t, x);
  u += 0x7FFFu + ((u >> 16) & 1u);  // RNE
  return (short)(u >> 16);
}

__device__ __forceinline__ void gload16(void* l, const void* g) {
  __builtin_amdgcn_global_load_lds(
      (const __attribute__((address_space(1))) void*)g,
      (__attribute__((address_space(3))) void*)l, 16, 0, 0);
}

__device__ __forceinline__ float gelu_tanh(float x) {
  float u = 0.7978845608028654f * (x + 0.044715f * x * x * x);
  float e = __expf(2.0f * u);
  return x - x / (e + 1.0f);
}

// Aq[m][:] = bf16(codebook[idx[m]][:])
__global__ void gather_cvt(const float* __restrict__ cb, const int* __restrict__ idx,
                           short* __restrict__ out) {
  int m = blockIdx.x * 2 + (threadIdx.x >> 7);
  int c = (threadIdx.x & 127) * 8;
  const float* s = cb + (size_t)idx[m] * 1024 + c;
  s16x8 o;
#pragma unroll
  for (int j = 0; j < 8; ++j) o[j] = f2bf(s[j]);
  *(s16x8*)(out + (size_t)m * 1024 + c) = o;
}

// in [K][N] fp32 -> out [N][K] bf16
__global__ void cvt_T(const float* __restrict__ in, short* __restrict__ out, int K, int N) {
  int Kb = K >> 3;
  int t = blockIdx.x * 256 + threadIdx.x;
  if (t >= N * Kb) return;
  int n = t / Kb;
  int k8 = (t - n * Kb) * 8;
  const float* s = in + (size_t)k8 * N + n;
  s16x8 o;
#pragma unroll
  for (int j = 0; j < 8; ++j) o[j] = f2bf(s[(size_t)j * N]);
  *(s16x8*)(out + (size_t)n * K + k8) = o;
}

// ---------------------------------------------------------------------------
// 192x256x64 bf16 GEMM: round-2's fine quadrant phases (proven 1244 TF busy)
// + round-9's deep buffering (A dbuf 1-tile ahead, B ring 2-tiles ahead,
// counted vmcnt(4), never 0) + 100%/75% exact grids.
// 8 waves 2M x 4N (per-wave 96x64 = 6x4 frags, acc = 96 AGPR).
// Per K-tile, 4 quadrant phases of 12 MFMA each:
//  P1 {ds af0+bf0; issue A(t+1)r0,r1; bar; lgkm0; prio; mh0xnh0; bar}
//  P2 {ds bf1;     issue A r2, B(t+2)r0;            mh0xnh1     }
//  P3 {ds af1;     issue B r1,r2;                   mh1xnh0     }
//  P4 {no ds;      issue B r3; mh1xnh1; vmcnt(4); bar}
// Ledger: per-tile issue order A,A,A,B,B,B,B -> newest-4 at P4 = B(t+2);
// vmcnt(4) proves A(t+1) + B(t+1) landed. A slack ~3 phases (L3 ok),
// B slack ~6 phases (HBM ok). All staged regions dead >=2 barriers prior.
// XOR-swizzled LDS (pre-swizzled source + swizzled ds_read; 0 conflicts),
// XCD-chunked row-major tile order.
// Grids: GEMM1 1536 = 6 exact rounds (100%), GEMM2 384 = 1.5 rounds (75%).
// MODE 1: epilogue bias+GELU -> bf16. MODE 2: epilogue bias -> fp32.
// ---------------------------------------------------------------------------
template <int MODE, int K, int N>
__global__ __launch_bounds__(512, 2) void gemmq(
    const short* __restrict__ A, const short* __restrict__ Bt,
    const float* __restrict__ bias, void* __restrict__ Cv) {
  constexpr int BM = 192, BN = 256;
  constexpr int AHS = BM * 64;    // 12288 shorts per A slot
  constexpr int BHS = BN * 64;    // 16384 shorts per B ring buffer
  constexpr int BB = 2 * AHS;     // B ring base (shorts)
  __shared__ short lds[2 * AHS + 3 * BHS];  // 73728 shorts = 147456 B

  constexpr int NBN = N / BN;
  const int nwg = gridDim.x;
  int swz = blockIdx.x;
  swz = (swz & 7) * (nwg >> 3) + (swz >> 3);  // XCD swizzle (nwg % 8 == 0)
  const int bm = swz / NBN, bn = swz - (swz / NBN) * NBN;  // row-major

  const int tid = threadIdx.x;
  const int wid = tid >> 6, lane = tid & 63;
  const int wr = wid >> 2, wc = wid & 3;  // per-wave C: 96 x 64
  const int lr = lane & 15, hi = lane >> 4;

  // staging: round = 64 rows (8KB); thread -> row (tid>>3), phys slot tid&7,
  // source fetches logical slot (tid&7)^(row&7) (inverse swizzle on source)
  const int sl = (tid & 7) ^ ((tid >> 3) & 7);
  const long rstep = (long)64 * K;
  const short* aptr = A + (long)(bm * BM + (tid >> 3)) * K + sl * 8;
  const short* bptr = Bt + (long)(bn * BN + (tid >> 3)) * K + sl * 8;
  const int wlds = wid * 512;  // wave's 1KB block within a staging round

  // ds_read bases; k-slot XOR-swizzled by row&7 (= lr&7: frag rows are x16,
  // wr*96 is a multiple of 8)
  const int aRB = (wr * 96 + lr) * 64;
  const int bRB = (wc * 64 + lr) * 64;
  const int sk0 = (hi ^ (lr & 7)) * 8;
  const int sk1 = ((4 + hi) ^ (lr & 7)) * 8;

  f32x4 acc[6][4] = {};
  s16x8 af[3][2], bf0[2][2], bf1[2][2];

  constexpr int NT = K >> 6;

  // prologue: A(0) -> slot0, B(0) -> ring0, B(1) -> ring1
#pragma unroll
  for (int r = 0; r < 3; ++r) gload16(&lds[r * 4096 + wlds], aptr + r * rstep);
#pragma unroll
  for (int r = 0; r < 4; ++r) gload16(&lds[BB + r * 4096 + wlds], bptr + r * rstep);
#pragma unroll
  for (int r = 0; r < 4; ++r) gload16(&lds[BB + BHS + r * 4096 + wlds], bptr + r * rstep + 64);
  asm volatile("s_waitcnt vmcnt(4)" ::: "memory");  // A(0),B(0) landed; B(1) flying
  __builtin_amdgcn_s_barrier();

  int rb0 = BB, rb1 = BB + BHS, rb2 = BB + 2 * BHS;  // read | next | write(t+2)

  for (int t = 0; t < NT; ++t) {
    const int ca = (t & 1) * AHS;  // current A slot
    const int na = AHS - ca;       // next A slot (dead since t-1's P3)
    const int ka = ((t + 1 < NT) ? (t + 1) : t) << 6;  // tail: dummy reload
    const int kb = ((t + 2 < NT) ? (t + 2) : t) << 6;

    // ---- P1: mh0 x nh0; stage A(t+1) r0,r1 ----
#pragma unroll
    for (int mi = 0; mi < 3; ++mi) {
      af[mi][0] = *(const s16x8*)&lds[ca + aRB + mi * 1024 + sk0];
      af[mi][1] = *(const s16x8*)&lds[ca + aRB + mi * 1024 + sk1];
    }
#pragma unroll
    for (int nj = 0; nj < 2; ++nj) {
      bf0[nj][0] = *(const s16x8*)&lds[rb0 + bRB + nj * 1024 + sk0];
      bf0[nj][1] = *(const s16x8*)&lds[rb0 + bRB + nj * 1024 + sk1];
    }
    gload16(&lds[na + 0 * 4096 + wlds], aptr + 0 * rstep + ka);
    gload16(&lds[na + 1 * 4096 + wlds], aptr + 1 * rstep + ka);
    __builtin_amdgcn_s_barrier();
    asm volatile("s_waitcnt lgkmcnt(0)" ::: "memory");
    __builtin_amdgcn_s_setprio(1);
#pragma unroll
    for (int mi = 0; mi < 3; ++mi)
#pragma unroll
      for (int nj = 0; nj < 2; ++nj)
#pragma unroll
        for (int ks = 0; ks < 2; ++ks)
          acc[mi][nj] = __builtin_amdgcn_mfma_f32_16x16x32_bf16(af[mi][ks], bf0[nj][ks], acc[mi][nj], 0, 0, 0);
    __builtin_amdgcn_s_setprio(0);
    __builtin_amdgcn_s_barrier();

    // ---- P2: mh0 x nh1; stage A(t+1) r2, B(t+2) r0 ----
#pragma unroll
    for (int nj = 0; nj < 2; ++nj) {
      bf1[nj][0] = *(const s16x8*)&lds[rb0 + bRB + (2 + nj) * 1024 + sk0];
      bf1[nj][1] = *(const s16x8*)&lds[rb0 + bRB + (2 + nj) * 1024 + sk1];
    }
    gload16(&lds[na + 2 * 4096 + wlds], aptr + 2 * rstep + ka);
    gload16(&lds[rb2 + 0 * 4096 + wlds], bptr + 0 * rstep + kb);
    __builtin_amdgcn_s_barrier();
    asm volatile("s_waitcnt lgkmcnt(0)" ::: "memory");
    __builtin_amdgcn_s_setprio(1);
#pragma unroll
    for (int mi = 0; mi < 3; ++mi)
#pragma unroll
      for (int nj = 0; nj < 2; ++nj)
#pragma unroll
        for (int ks = 0; ks < 2; ++ks)
          acc[mi][2 + nj] = __builtin_amdgcn_mfma_f32_16x16x32_bf16(af[mi][ks], bf1[nj][ks], acc[mi][2 + nj], 0, 0, 0);
    __builtin_amdgcn_s_setprio(0);
    __builtin_amdgcn_s_barrier();

    // ---- P3: mh1 x nh0; stage B(t+2) r1,r2 ----
#pragma unroll
    for (int mi = 0; mi < 3; ++mi) {
      af[mi][0] = *(const s16x8*)&lds[ca + aRB + (3 + mi) * 1024 + sk0];
      af[mi][1] = *(const s16x8*)&lds[ca + aRB + (3 + mi) * 1024 + sk1];
    }
    gload16(&lds[rb2 + 1 * 4096 + wlds], bptr + 1 * rstep + kb);
    gload16(&lds[rb2 + 2 * 4096 + wlds], bptr + 2 * rstep + kb);
    __builtin_amdgcn_s_barrier();
    asm volatile("s_waitcnt lgkmcnt(0)" ::: "memory");
    __builtin_amdgcn_s_setprio(1);
#pragma unroll
    for (int mi = 0; mi < 3; ++mi)
#pragma unroll
      for (int nj = 0; nj < 2; ++nj)
#pragma unroll
        for (int ks = 0; ks < 2; ++ks)
          acc[3 + mi][nj] = __builtin_amdgcn_mfma_f32_16x16x32_bf16(af[mi][ks], bf0[nj][ks], acc[3 + mi][nj], 0, 0, 0);
    __builtin_amdgcn_s_setprio(0);
    __builtin_amdgcn_s_barrier();

    // ---- P4: mh1 x nh1 (no ds reads); stage B(t+2) r3; vmcnt(4) ----
    gload16(&lds[rb2 + 3 * 4096 + wlds], bptr + 3 * rstep + kb);
    __builtin_amdgcn_s_setprio(1);
#pragma unroll
    for (int mi = 0; mi < 3; ++mi)
#pragma unroll
      for (int nj = 0; nj < 2; ++nj)
#pragma unroll
        for (int ks = 0; ks < 2; ++ks)
          acc[3 + mi][2 + nj] = __builtin_amdgcn_mfma_f32_16x16x32_bf16(af[mi][ks], bf1[nj][ks], acc[3 + mi][2 + nj], 0, 0, 0);
    __builtin_amdgcn_s_setprio(0);
    // issue order this tile: A,A,A,B,B,B,B -> keep newest 4 = B(t+2) only
    asm volatile("s_waitcnt vmcnt(4)" ::: "memory");
    __builtin_amdgcn_s_barrier();
    const int tmp = rb0; rb0 = rb1; rb1 = rb2; rb2 = tmp;
  }

  // epilogue: C/D layout col=lane&15, row=(lane>>4)*4+r
  const int m0 = bm * BM + wr * 96 + hi * 4;
  const int n0 = bn * BN + wc * 64 + lr;
#pragma unroll
  for (int nj = 0; nj < 4; ++nj) {
    const int n = n0 + nj * 16;
    const float bv = bias[n];
#pragma unroll
    for (int mi = 0; mi < 6; ++mi) {
      f32x4 v = acc[mi][nj];
#pragma unroll
      for (int r = 0; r < 4; ++r) {
        const int m = m0 + mi * 16 + r;
        float x = v[r] + bv;
        if (MODE == 1) {
          ((short*)Cv)[(size_t)m * N + n] = f2bf(gelu_tanh(x));
        } else {
          ((float*)Cv)[(size_t)m * N + n] = x;
        }
      }
    }
  }
}

extern "C" void kernel_launch(void* const* d_in, const int* in_sizes, int n_in,
                              void* d_out, int out_size, void* d_ws, size_t ws_size,
                              hipStream_t stream) {
  const int* idx = (const int*)d_in[0];
  const float* cb = (const float*)d_in[1];
  const float* W1 = (const float*)d_in[2];
  const float* b1 = (const float*)d_in[3];
  const float* W2 = (const float*)d_in[4];
  const float* b2 = (const float*)d_in[5];
  float* out = (float*)d_out;

  const int Mtot = 32 * 576;  // 18432 = 96 * 192

  // ws: Aq 40MB | W1T 8MB | W2T 8MB | h chunk
  char* ws = (char*)d_ws;
  short* aq = (short*)(ws);
  short* w1t = (short*)(ws + (size_t)40 * 1024 * 1024);
  short* w2t = (short*)(ws + (size_t)48 * 1024 * 1024);
  short* h = (short*)(ws + (size_t)56 * 1024 * 1024);

  gather_cvt<<<Mtot / 2, 256, 0, stream>>>(cb, idx, aq);
  cvt_T<<<2048, 256, 0, stream>>>(W1, w1t, 1024, 4096);  // -> [4096][1024]
  cvt_T<<<2048, 256, 0, stream>>>(W2, w2t, 4096, 1024);  // -> [1024][4096]

  size_t avail = (ws_size > (size_t)56 * 1024 * 1024) ? ws_size - (size_t)56 * 1024 * 1024 : 0;
  int nc = 1;
  while (nc < 8 && (size_t)(Mtot / nc) * 8192 > avail) nc <<= 1;
  const int Mc = Mtot / nc;  // Mc/192 = 96/nc, integer for nc in {1,2,4,8}

  for (int c = 0; c < nc; ++c) {
    gemmq<1, 1024, 4096><<<(Mc / 192) * 16, 512, 0, stream>>>(
        aq + (size_t)c * Mc * 1024, w1t, b1, (void*)h);
    gemmq<2, 4096, 1024><<<(Mc / 192) * 4, 512, 0, stream>>>(
        h, w2t, b2, (void*)(out + (size_t)c * Mc * 1024));
  }
}

// Round 12
// 425.877 us; speedup vs baseline: 1.0493x; 1.0493x over previous
//
#include <hip/hip_runtime.h>
#include <stdint.h>

typedef __attribute__((ext_vector_type(8))) short s16x8;
typedef __attribute__((ext_vector_type(4))) float f32x4;

__device__ __forceinline__ short f2bf(float x) {
  uint32_t u = __builtin_bit_cast(uint32_t, x);
  u += 0x7FFFu + ((u >> 16) & 1u);  // RNE
  return (short)(u >> 16);
}

__device__ __forceinline__ void gload16(void* l, const void* g) {
  __builtin_amdgcn_global_load_lds(
      (const __attribute__((address_space(1))) void*)g,
      (__attribute__((address_space(3))) void*)l, 16, 0, 0);
}

__device__ __forceinline__ float gelu_tanh(float x) {
  float u = 0.7978845608028654f * (x + 0.044715f * x * x * x);
  float e = __expf(2.0f * u);
  return x - x / (e + 1.0f);
}

// Aq[m][:] = bf16(codebook[idx[m]][:])
__global__ void gather_cvt(const float* __restrict__ cb, const int* __restrict__ idx,
                           short* __restrict__ out) {
  int m = blockIdx.x * 2 + (threadIdx.x >> 7);
  int c = (threadIdx.x & 127) * 8;
  const float* s = cb + (size_t)idx[m] * 1024 + c;
  s16x8 o;
#pragma unroll
  for (int j = 0; j < 8; ++j) o[j] = f2bf(s[j]);
  *(s16x8*)(out + (size_t)m * 1024 + c) = o;
}

// in [K][N] fp32 -> out [N][K] bf16
__global__ void cvt_T(const float* __restrict__ in, short* __restrict__ out, int K, int N) {
  int Kb = K >> 3;
  int t = blockIdx.x * 256 + threadIdx.x;
  if (t >= N * Kb) return;
  int n = t / Kb;
  int k8 = (t - n * Kb) * 8;
  const float* s = in + (size_t)k8 * N + n;
  s16x8 o;
#pragma unroll
  for (int j = 0; j < 8; ++j) o[j] = f2bf(s[(size_t)j * N]);
  *(s16x8*)(out + (size_t)n * K + k8) = o;
}

// ---------------------------------------------------------------------------
// 192x256x64 bf16 GEMM, R9 skeleton (best measured):
//   8 waves 2M x 4N (per-wave 96x64 = 6x4 frags, acc = 96 AGPR),
//   A double-buffered (issued at tile top), B triple-buffered ring (2-tile
//   lookahead), ONE barrier + one counted vmcnt(4) per K-tile (never 0),
//   XOR-swizzled LDS (pre-swizzled source + swizzled ds_read, 0 conflicts).
// NEW (round 11): 2D XCD-chunked tile mapping. Diagnosis from R9 counters:
//   full-grid rounds run 2.08us/K-tile but the half-grid tail runs ~2x
//   faster => memory-fabric contention-bound (~7 TB/s demand). Old 1D chunk
//   gave each XCD 12bm x ALL 16bn -> 32 concurrent blocks touch 8 MB of B
//   > 4 MB L2 -> B re-streamed from L3/HBM per bm-group (FETCH 215 MB vs
//   8 MB W1T). New mapping: XCD = bid&7 (HW round-robin premise, m157),
//   each XCD owns a 24bm x (NBN/2)bn rectangle, bn-inner order ->
//   concurrent working set = 8 B-panels (GEMM1) / 2 (GEMM2) = 4 MB = L2.
//   B now fetched from L3 ~once per XCD.
// Grids: GEMM1 1536 = 6.0 rounds (100%), GEMM2 384 = 1.5 rounds (75%,
// tail round is contention-relieved so cheaper than it looks).
// MODE 1: epilogue bias+GELU -> bf16. MODE 2: epilogue bias -> fp32.
// ---------------------------------------------------------------------------
template <int MODE, int K, int N>
__global__ __launch_bounds__(512, 2) void gemmx(
    const short* __restrict__ A, const short* __restrict__ Bt,
    const float* __restrict__ bias, void* __restrict__ Cv) {
  constexpr int BM = 192, BN = 256;
  constexpr int AHS = BM * 64;    // 12288 shorts per A slot
  constexpr int BHS = BN * 64;    // 16384 shorts per B ring buffer
  constexpr int BB = 2 * AHS;     // B ring base (shorts)
  __shared__ short lds[2 * AHS + 3 * BHS];  // 73728 shorts = 147456 B

  constexpr int NBN = N / BN;      // 16 (GEMM1) or 4 (GEMM2)
  constexpr int RBN = NBN / 2;     // XCD region bn-width (XBN = 2)
  const int nwg = gridDim.x;       // % 8 == 0 by construction
  const int xcd = blockIdx.x & 7;  // HW round-robin premise
  const int c = blockIdx.x >> 3;   // index within this XCD's chunk
  const int RBM = (nwg >> 3) / RBN;  // XCD region bm-height (XBM = 4)
  const int lbm = c / RBN, lbn = c - (c / RBN) * RBN;  // bn-inner order
  const int bm = (xcd >> 1) * RBM + lbm;
  const int bn = (xcd & 1) * RBN + lbn;

  const int tid = threadIdx.x;
  const int wid = tid >> 6, lane = tid & 63;
  const int wr = wid >> 2, wc = wid & 3;  // per-wave C: 96 x 64
  const int lr = lane & 15, hi = lane >> 4;

  // staging: round = 64 rows (8KB); thread -> row (tid>>3), phys slot tid&7,
  // source fetches logical slot (tid&7)^(row&7) (inverse swizzle on source)
  const int sl = (tid & 7) ^ ((tid >> 3) & 7);
  const long rstep = (long)64 * K;
  const short* aptr = A + (long)(bm * BM + (tid >> 3)) * K + sl * 8;
  const short* bptr = Bt + (long)(bn * BN + (tid >> 3)) * K + sl * 8;
  const int wlds = wid * 512;  // wave's 1KB block within a staging round

  // ds_read bases; k-slot XOR-swizzled by row&7 (= lr&7: frag rows are x16,
  // wr*96 is a multiple of 8)
  const int aRB = (wr * 96 + lr) * 64;
  const int bRB = (wc * 64 + lr) * 64;
  const int sk0 = (hi ^ (lr & 7)) * 8;
  const int sk1 = ((4 + hi) ^ (lr & 7)) * 8;

  f32x4 acc[6][4] = {};
  s16x8 af[3][2], bf[4][2];

  constexpr int NT = K >> 6;

  // prologue: A(0) -> slot0 (3 rounds), B(0) -> ring0, B(1) -> ring1
#pragma unroll
  for (int r = 0; r < 3; ++r) gload16(&lds[r * 4096 + wlds], aptr + r * rstep);
#pragma unroll
  for (int r = 0; r < 4; ++r) gload16(&lds[BB + r * 4096 + wlds], bptr + r * rstep);
#pragma unroll
  for (int r = 0; r < 4; ++r) gload16(&lds[BB + BHS + r * 4096 + wlds], bptr + r * rstep + 64);
  asm volatile("s_waitcnt vmcnt(4)" ::: "memory");  // A(0),B(0) landed; B(1) flying
  __builtin_amdgcn_s_barrier();

  int rb0 = BB, rb1 = BB + BHS, rb2 = BB + 2 * BHS;  // read | next | write(t+2)

  for (int t = 0; t < NT; ++t) {
    const int ca = (t & 1) * AHS;  // current A slot
    const int na = AHS - ca;       // next A slot (holds retired A(t-1))
    const int ka = ((t + 1 < NT) ? (t + 1) : t) << 6;  // tail: dummy reload, slot unread
    const int kb = ((t + 2 < NT) ? (t + 2) : t) << 6;

    // issue A(t+1) at tile top: full-tile slack, L2-warm panel
#pragma unroll
    for (int r = 0; r < 3; ++r) gload16(&lds[na + r * 4096 + wlds], aptr + r * rstep + ka);

    // ---- half 1: m-frags 0-2 x all 4 n-frags ----
#pragma unroll
    for (int mi = 0; mi < 3; ++mi) {
      af[mi][0] = *(const s16x8*)&lds[ca + aRB + mi * 1024 + sk0];
      af[mi][1] = *(const s16x8*)&lds[ca + aRB + mi * 1024 + sk1];
    }
#pragma unroll
    for (int nj = 0; nj < 4; ++nj) {
      bf[nj][0] = *(const s16x8*)&lds[rb0 + bRB + nj * 1024 + sk0];
      bf[nj][1] = *(const s16x8*)&lds[rb0 + bRB + nj * 1024 + sk1];
    }
    asm volatile("s_waitcnt lgkmcnt(0)" ::: "memory");
    __builtin_amdgcn_s_setprio(1);
#pragma unroll
    for (int mi = 0; mi < 3; ++mi)
#pragma unroll
      for (int nj = 0; nj < 4; ++nj)
#pragma unroll
        for (int ks = 0; ks < 2; ++ks)
          acc[mi][nj] = __builtin_amdgcn_mfma_f32_16x16x32_bf16(af[mi][ks], bf[nj][ks], acc[mi][nj], 0, 0, 0);
    __builtin_amdgcn_s_setprio(0);

    // ---- half 2: m-frags 3-5; issue B(t+2) into ring write slot ----
#pragma unroll
    for (int r = 0; r < 4; ++r)
      gload16(&lds[rb2 + r * 4096 + wlds], bptr + r * rstep + kb);
#pragma unroll
    for (int mi = 0; mi < 3; ++mi) {
      af[mi][0] = *(const s16x8*)&lds[ca + aRB + (3 + mi) * 1024 + sk0];
      af[mi][1] = *(const s16x8*)&lds[ca + aRB + (3 + mi) * 1024 + sk1];
    }
    asm volatile("s_waitcnt lgkmcnt(0)" ::: "memory");
    __builtin_amdgcn_s_setprio(1);
#pragma unroll
    for (int mi = 0; mi < 3; ++mi)
#pragma unroll
      for (int nj = 0; nj < 4; ++nj)
#pragma unroll
        for (int ks = 0; ks < 2; ++ks)
          acc[3 + mi][nj] = __builtin_amdgcn_mfma_f32_16x16x32_bf16(af[mi][ks], bf[nj][ks], acc[3 + mi][nj], 0, 0, 0);
    __builtin_amdgcn_s_setprio(0);

    // queue (old->new): B(t+1)x4, A(t+1)x3, B(t+2)x4 -> keep 4 = B(t+2) only
    asm volatile("s_waitcnt vmcnt(4)" ::: "memory");
    __builtin_amdgcn_s_barrier();
    const int tmp = rb0; rb0 = rb1; rb1 = rb2; rb2 = tmp;
  }

  // epilogue: C/D layout col=lane&15, row=(lane>>4)*4+r
  const int m0 = bm * BM + wr * 96 + hi * 4;
  const int n0 = bn * BN + wc * 64 + lr;
#pragma unroll
  for (int nj = 0; nj < 4; ++nj) {
    const int n = n0 + nj * 16;
    const float bv = bias[n];
#pragma unroll
    for (int mi = 0; mi < 6; ++mi) {
      f32x4 v = acc[mi][nj];
#pragma unroll
      for (int r = 0; r < 4; ++r) {
        const int m = m0 + mi * 16 + r;
        float x = v[r] + bv;
        if (MODE == 1) {
          ((short*)Cv)[(size_t)m * N + n] = f2bf(gelu_tanh(x));
        } else {
          ((float*)Cv)[(size_t)m * N + n] = x;
        }
      }
    }
  }
}

extern "C" void kernel_launch(void* const* d_in, const int* in_sizes, int n_in,
                              void* d_out, int out_size, void* d_ws, size_t ws_size,
                              hipStream_t stream) {
  const int* idx = (const int*)d_in[0];
  const float* cb = (const float*)d_in[1];
  const float* W1 = (const float*)d_in[2];
  const float* b1 = (const float*)d_in[3];
  const float* W2 = (const float*)d_in[4];
  const float* b2 = (const float*)d_in[5];
  float* out = (float*)d_out;

  const int Mtot = 32 * 576;  // 18432 = 96 * 192

  // ws: Aq 40MB | W1T 8MB | W2T 8MB | h chunk
  char* ws = (char*)d_ws;
  short* aq = (short*)(ws);
  short* w1t = (short*)(ws + (size_t)40 * 1024 * 1024);
  short* w2t = (short*)(ws + (size_t)48 * 1024 * 1024);
  short* h = (short*)(ws + (size_t)56 * 1024 * 1024);

  gather_cvt<<<Mtot / 2, 256, 0, stream>>>(cb, idx, aq);
  cvt_T<<<2048, 256, 0, stream>>>(W1, w1t, 1024, 4096);  // -> [4096][1024]
  cvt_T<<<2048, 256, 0, stream>>>(W2, w2t, 4096, 1024);  // -> [1024][4096]

  size_t avail = (ws_size > (size_t)56 * 1024 * 1024) ? ws_size - (size_t)56 * 1024 * 1024 : 0;
  int nc = 1;
  while (nc < 8 && (size_t)(Mtot / nc) * 8192 > avail) nc <<= 1;
  const int Mc = Mtot / nc;  // Mc/192 = 96/nc, integer for nc in {1,2,4,8}

  for (int c = 0; c < nc; ++c) {
    gemmx<1, 1024, 4096><<<(Mc / 192) * 16, 512, 0, stream>>>(
        aq + (size_t)c * Mc * 1024, w1t, b1, (void*)h);
    gemmx<2, 4096, 1024><<<(Mc / 192) * 4, 512, 0, stream>>>(
        h, w2t, b2, (void*)(out + (size_t)c * Mc * 1024));
  }
}